// Round 9
// baseline (842.621 us; speedup 1.0000x reference)
//
#include <hip/hip_runtime.h>
#include <hip/hip_cooperative_groups.h>
#include <hip/hip_bf16.h>
#include <math.h>

namespace cg = cooperative_groups;

#define DMODEL 512
#define NHEAD  8
#define DHEAD  64

typedef __attribute__((ext_vector_type(8))) short bf16x8;
typedef __attribute__((ext_vector_type(4))) float f32x4;
typedef __attribute__((ext_vector_type(4))) short short4v;

static __device__ inline short f2bf(float f) {
    __hip_bfloat16 h = __float2bfloat16(f);
    return *reinterpret_cast<short*>(&h);
}

#define GLOAD_LDS16(gp, lp)                                                      \
    __builtin_amdgcn_global_load_lds(                                            \
        (const __attribute__((address_space(1))) unsigned int*)(gp),             \
        (__attribute__((address_space(3))) unsigned int*)(lp), 16, 0, 0)

struct GJob {
    const short* A; const short* W;
    const float* bias; const float* resid;
    void* C; int N; int K; float scale; int relu; int obf; int ntile;
};

struct MegaArgs {
    const float* wsrc[10]; short* wdst[10]; int wn[10];
    const float* dec; const float* enc;
    const float* slf_g; const float* slf_b;
    const float* encln_g; const float* encln_b;
    const float* ffnln_g; const float* ffnln_b;
    const float* fb1; const float* fb2;
    short* qn16; short* dec16; short* enc16; short* q16; short* ao16;
    short* kv16; short* kv16e; short* h16;
    float* x1; float* x2; float* out;
};

// ---------------- LayerNorm helper: 4 rows per 256-thread block ----------------
__device__ __forceinline__ void ln_rows(const float* __restrict__ X,
                                        const float* __restrict__ gam,
                                        const float* __restrict__ bet,
                                        short* __restrict__ Y, int rowbase) {
    int row = rowbase + (threadIdx.x >> 6);
    int tid = threadIdx.x & 63;
    const float* x = X + (size_t)row * DMODEL;
    float4 a = *(const float4*)(x + tid * 4);
    float4 b = *(const float4*)(x + 256 + tid * 4);
    float sum = a.x + a.y + a.z + a.w + b.x + b.y + b.z + b.w;
    float sq  = a.x*a.x + a.y*a.y + a.z*a.z + a.w*a.w
              + b.x*b.x + b.y*b.y + b.z*b.z + b.w*b.w;
#pragma unroll
    for (int off = 1; off < 64; off <<= 1) {
        sum += __shfl_xor(sum, off);
        sq  += __shfl_xor(sq, off);
    }
    float mu  = sum * (1.0f / DMODEL);
    float var = sq * (1.0f / DMODEL) - mu * mu;
    float r   = rsqrtf(var + 1e-6f);
    float4 g1 = *(const float4*)(gam + tid * 4);
    float4 c1 = *(const float4*)(bet + tid * 4);
    float4 g2 = *(const float4*)(gam + 256 + tid * 4);
    float4 c2 = *(const float4*)(bet + 256 + tid * 4);
    short4v y1, y2;
    y1.x = f2bf((a.x - mu) * r * g1.x + c1.x);
    y1.y = f2bf((a.y - mu) * r * g1.y + c1.y);
    y1.z = f2bf((a.z - mu) * r * g1.z + c1.z);
    y1.w = f2bf((a.w - mu) * r * g1.w + c1.w);
    y2.x = f2bf((b.x - mu) * r * g2.x + c2.x);
    y2.y = f2bf((b.y - mu) * r * g2.y + c2.y);
    y2.z = f2bf((b.z - mu) * r * g2.z + c2.z);
    y2.w = f2bf((b.w - mu) * r * g2.w + c2.w);
    short* y = Y + (size_t)row * DMODEL;
    *(short4v*)(y + tid * 4)       = y1;
    *(short4v*)(y + 256 + tid * 4) = y2;
}

// ---------------- GEMM tile: 64x64 block, 4 waves (2x2 of 32x32), BK=64, dbuf ----------------
__device__ __forceinline__ void gemm_tile(const GJob& jb, int bid,
                                          short* AS0, short* BS0) {
    const short* __restrict__ A = jb.A;
    const short* __restrict__ W = jb.W;
    const int N = jb.N, K = jb.K;
    const int nbx = N >> 6;
    const int tn = (bid % nbx) * 64;
    const int tm = (bid / nbx) * 64;
    const int tid  = threadIdx.x;
    const int w    = tid >> 6;
    const int l    = tid & 63;
    const int lq   = l & 15;
    const int g    = l >> 4;
    const int wm   = (w >> 1) * 32;
    const int wn   = (w & 1) * 32;
    const int lrow = l >> 3;
    const int lsl  = l & 7;

    f32x4 acc[2][2];
#pragma unroll
    for (int i = 0; i < 2; ++i)
#pragma unroll
        for (int jj = 0; jj < 2; ++jj)
            acc[i][jj] = (f32x4){0.f, 0.f, 0.f, 0.f};

    __syncthreads();   // guard LDS reuse across virtual tiles / phases

#define GSTAGE(buf, koff)                                                        \
    do {                                                                         \
        _Pragma("unroll")                                                        \
        for (int i_ = 0; i_ < 2; ++i_) {                                         \
            int row_ = i_ * 32 + w * 8 + lrow;                                   \
            int slot_ = lsl ^ (row_ & 7);                                        \
            GLOAD_LDS16(A + (size_t)(tm + row_) * K + (koff) + slot_ * 8,        \
                        AS0 + (buf) * 4096 + i_ * 2048 + w * 512);               \
            GLOAD_LDS16(W + (size_t)(tn + row_) * K + (koff) + slot_ * 8,        \
                        BS0 + (buf) * 4096 + i_ * 2048 + w * 512);               \
        }                                                                        \
    } while (0)

    GSTAGE(0, 0);
    int buf = 0;
#pragma unroll 1
    for (int k0 = 0; k0 < K; k0 += 64, buf ^= 1) {
        __syncthreads();
        if (k0 + 64 < K) GSTAGE(buf ^ 1, k0 + 64);
        const short* As = AS0 + buf * 4096;
        const short* Bs = BS0 + buf * 4096;
#pragma unroll
        for (int ks = 0; ks < 2; ++ks) {
            const int sl = ((ks * 4 + g) ^ (lq & 7)) * 8;
            bf16x8 af[2], bfv[2];
#pragma unroll
            for (int i = 0; i < 2; ++i) {
                af[i]  = *(const bf16x8*)&As[(wm + i * 16 + lq) * 64 + sl];
                bfv[i] = *(const bf16x8*)&Bs[(wn + i * 16 + lq) * 64 + sl];
            }
#pragma unroll
            for (int i = 0; i < 2; ++i)
#pragma unroll
                for (int jj = 0; jj < 2; ++jj)
                    acc[i][jj] = __builtin_amdgcn_mfma_f32_16x16x32_bf16(
                        af[i], bfv[jj], acc[i][jj], 0, 0, 0);
        }
    }
#undef GSTAGE

#pragma unroll
    for (int i = 0; i < 2; ++i) {
#pragma unroll
        for (int r = 0; r < 4; ++r) {
            int row = tm + wm + i * 16 + g * 4 + r;
#pragma unroll
            for (int jj = 0; jj < 2; ++jj) {
                int col = tn + wn + jj * 16 + lq;
                float v = acc[i][jj][r] * jb.scale;
                if (jb.bias)  v += jb.bias[col];
                if (jb.resid) v += jb.resid[(size_t)row * N + col];
                if (jb.relu)  v = fmaxf(v, 0.f);
                if (jb.obf) ((short*)jb.C)[(size_t)row * N + col] = f2bf(v);
                else        ((float*)jb.C)[(size_t)row * N + col] = v;
            }
        }
    }
}

// ---------------- Flash attention block: 4 waves x 16 q-rows, single-buf ----------------
// Kt: 4096 shorts [key][d] swizzled; Vt: stride 72 [d][key]; Pb: wave*1152 + q*72 + k
__device__ __forceinline__ void attn_block(
        const short* __restrict__ Q, const short* __restrict__ K,
        const short* __restrict__ V, short* __restrict__ O,
        int causal, int band, int bh,
        short* Kt, short* Vt, short* Pb) {
    const int Lq = 1024, Lk = 1024, qs = DMODEL, kvs = 1024;
    const int tid  = threadIdx.x;
    const int wave = tid >> 6;
    const int lane = tid & 63;
    const int lq   = lane & 15;
    const int g    = lane >> 4;
    const int b = bh >> 3, h = bh & 7;
    const int qt = band * 4 + wave;
    const int q0 = qt * 16;
    const float NEG = -__builtin_inff();

    size_t qoff = (size_t)(b * Lq + q0 + lq) * qs + h * DHEAD;
    bf16x8 qf0 = *(const bf16x8*)(Q + qoff + g * 8);
    bf16x8 qf1 = *(const bf16x8*)(Q + qoff + 32 + g * 8);

    f32x4 o[4] = {{0,0,0,0},{0,0,0,0},{0,0,0,0},{0,0,0,0}};
    f32x4 lacc = {0.f, 0.f, 0.f, 0.f};

    bf16x8 ones;
    {
        short ov = (lq == 0) ? (short)0x3F80 : (short)0;
#pragma unroll
        for (int i = 0; i < 8; ++i) ones[i] = ov;
    }

    const int nkt = causal ? (band + 1) : (Lk >> 6);
    const int lrow = lane >> 3;
    const int lsl  = lane & 7;
    const int va = tid & 31;
    const int vd = (tid >> 5) * 8;

#pragma unroll 1
    for (int kt = 0; kt < nkt; ++kt) {
        __syncthreads();
#pragma unroll
        for (int i = 0; i < 2; ++i) {
            int row = i * 32 + wave * 8 + lrow;
            int slot = lsl ^ (row & 7);
            GLOAD_LDS16(K + (size_t)(b * Lk + kt * 64 + row) * kvs + h * DHEAD + slot * 8,
                        Kt + i * 2048 + wave * 512);
        }
        {
            size_t gb = (size_t)(b * Lk + kt * 64 + 2 * va) * kvs + h * DHEAD + vd;
            bf16x8 v0 = *(const bf16x8*)(V + gb);
            bf16x8 v1 = *(const bf16x8*)(V + gb + kvs);
#pragma unroll
            for (int i = 0; i < 8; ++i) {
                unsigned p = (unsigned short)v0[i] | ((unsigned)(unsigned short)v1[i] << 16);
                *(unsigned*)&Vt[(vd + i) * 72 + 2 * va] = p;
            }
        }
        __syncthreads();

        // ---- S^T = K Q^T ----
        f32x4 s[4];
#pragma unroll
        for (int sub = 0; sub < 4; ++sub) {
            int rr = sub * 16 + lq;
            const int sl0 = ((0 + g) ^ (lq & 7)) * 8;
            const int sl1 = ((4 + g) ^ (lq & 7)) * 8;
            bf16x8 kf0 = *(const bf16x8*)&Kt[rr * 64 + sl0];
            bf16x8 kf1 = *(const bf16x8*)&Kt[rr * 64 + sl1];
            f32x4 a = {0.f, 0.f, 0.f, 0.f};
            a = __builtin_amdgcn_mfma_f32_16x16x32_bf16(kf0, qf0, a, 0, 0, 0);
            a = __builtin_amdgcn_mfma_f32_16x16x32_bf16(kf1, qf1, a, 0, 0, 0);
            s[sub] = a;
        }
        if (causal && kt == nkt - 1) {
            int qg = q0 + lq;
#pragma unroll
            for (int sub = 0; sub < 4; ++sub) {
#pragma unroll
                for (int r = 0; r < 4; ++r) {
                    int kg = kt * 64 + sub * 16 + g * 4 + r;
                    if (kg > qg) s[sub][r] = NEG;
                }
            }
        }

        // ---- P = exp2(S) (log2e folded into Q-proj) + packed write ----
#pragma unroll
        for (int sub = 0; sub < 4; ++sub) {
            short4v p4;
            p4.x = f2bf(exp2f(fminf(s[sub][0], 85.f)));
            p4.y = f2bf(exp2f(fminf(s[sub][1], 85.f)));
            p4.z = f2bf(exp2f(fminf(s[sub][2], 85.f)));
            p4.w = f2bf(exp2f(fminf(s[sub][3], 85.f)));
            *(short4v*)&Pb[wave * 1152 + lq * 72 + sub * 16 + g * 4] = p4;
        }
        bf16x8 pf0 = *(const bf16x8*)&Pb[wave * 1152 + lq * 72 + g * 8];
        bf16x8 pf1 = *(const bf16x8*)&Pb[wave * 1152 + lq * 72 + 32 + g * 8];

        // ---- O += P V ; l += P @ ones ----
#pragma unroll
        for (int dc = 0; dc < 4; ++dc) {
            bf16x8 vf0 = *(const bf16x8*)&Vt[(dc * 16 + lq) * 72 + g * 8];
            bf16x8 vf1 = *(const bf16x8*)&Vt[(dc * 16 + lq) * 72 + 32 + g * 8];
            o[dc] = __builtin_amdgcn_mfma_f32_16x16x32_bf16(pf0, vf0, o[dc], 0, 0, 0);
            o[dc] = __builtin_amdgcn_mfma_f32_16x16x32_bf16(pf1, vf1, o[dc], 0, 0, 0);
        }
        lacc = __builtin_amdgcn_mfma_f32_16x16x32_bf16(pf0, ones, lacc, 0, 0, 0);
        lacc = __builtin_amdgcn_mfma_f32_16x16x32_bf16(pf1, ones, lacc, 0, 0, 0);
    }

#pragma unroll
    for (int r = 0; r < 4; ++r) {
        float lr = __shfl(lacc[r], g << 4);
        float inv = 1.f / lr;
        size_t ob = (size_t)(b * Lq + q0 + g * 4 + r) * qs + h * DHEAD + lq;
        O[ob + 0]  = f2bf(o[0][r] * inv);
        O[ob + 16] = f2bf(o[1][r] * inv);
        O[ob + 32] = f2bf(o[2][r] * inv);
        O[ob + 48] = f2bf(o[3][r] * inv);
    }
}

// ============================ Persistent cooperative megakernel ============================
// 512 blocks x 256 threads, 11 phases with grid.sync between dependent phases.
// __launch_bounds__(256,2) + 32KB LDS guarantee >=2 blocks/CU -> 512 co-resident.
__global__ __launch_bounds__(256, 2) void mega_kernel(MegaArgs a) {
    cg::grid_group grid = cg::this_grid();
    __shared__ short smem[16384];          // 32 KB, aliased per phase
    short* AS0 = smem;                     // gemm: As dbuf [0,8192)
    short* BS0 = smem + 8192;              //       Bs dbuf [8192,16384)
    short* Kt  = smem;                     // attn: Kt 4096
    short* Vt  = smem + 4096;              //       Vt 64*72 = 4608
    short* Pb  = smem + 4096 + 4608;       //       Pb 4*16*72 = 4608

    const int bx = blockIdx.x;
    const int nb = gridDim.x;
    const float QSCALE = 0.125f * 1.44269504f;   // 1/sqrt(dk) * log2(e)

    // ---- phase 0: prep (LN1 + dec/enc cvt + weight cvt) ----
#pragma unroll 1
    for (int v = bx; v < 1024 + 1280; v += nb) {
        if (v < 1024) {
            int row = v * 4 + (threadIdx.x >> 6);
            int tid = threadIdx.x & 63;
            const float* x = a.dec + (size_t)row * DMODEL;
            float4 v0 = *(const float4*)(x + tid * 4);
            float4 v1 = *(const float4*)(x + 256 + tid * 4);
            float sum = v0.x + v0.y + v0.z + v0.w + v1.x + v1.y + v1.z + v1.w;
            float sq  = v0.x*v0.x + v0.y*v0.y + v0.z*v0.z + v0.w*v0.w
                      + v1.x*v1.x + v1.y*v1.y + v1.z*v1.z + v1.w*v1.w;
#pragma unroll
            for (int off = 1; off < 64; off <<= 1) {
                sum += __shfl_xor(sum, off);
                sq  += __shfl_xor(sq, off);
            }
            float mu  = sum * (1.0f / DMODEL);
            float var = sq * (1.0f / DMODEL) - mu * mu;
            float r   = rsqrtf(var + 1e-6f);
            float4 g1 = *(const float4*)(a.slf_g + tid * 4);
            float4 c1 = *(const float4*)(a.slf_b + tid * 4);
            float4 g2 = *(const float4*)(a.slf_g + 256 + tid * 4);
            float4 c2 = *(const float4*)(a.slf_b + 256 + tid * 4);
            short4v y1, y2;
            y1.x = f2bf((v0.x - mu) * r * g1.x + c1.x);
            y1.y = f2bf((v0.y - mu) * r * g1.y + c1.y);
            y1.z = f2bf((v0.z - mu) * r * g1.z + c1.z);
            y1.w = f2bf((v0.w - mu) * r * g1.w + c1.w);
            y2.x = f2bf((v1.x - mu) * r * g2.x + c2.x);
            y2.y = f2bf((v1.y - mu) * r * g2.y + c2.y);
            y2.z = f2bf((v1.z - mu) * r * g2.z + c2.z);
            y2.w = f2bf((v1.w - mu) * r * g2.w + c2.w);
            short* y = a.qn16 + (size_t)row * DMODEL;
            *(short4v*)(y + tid * 4)       = y1;
            *(short4v*)(y + 256 + tid * 4) = y2;
            // dec16
            short4v d1, d2;
            d1.x = f2bf(v0.x); d1.y = f2bf(v0.y); d1.z = f2bf(v0.z); d1.w = f2bf(v0.w);
            d2.x = f2bf(v1.x); d2.y = f2bf(v1.y); d2.z = f2bf(v1.z); d2.w = f2bf(v1.w);
            short* d = a.dec16 + (size_t)row * DMODEL;
            *(short4v*)(d + tid * 4)       = d1;
            *(short4v*)(d + 256 + tid * 4) = d2;
            // enc16
            const float* e = a.enc + (size_t)row * DMODEL;
            float4 ea = *(const float4*)(e + tid * 4);
            float4 eb = *(const float4*)(e + 256 + tid * 4);
            short4v e1, e2;
            e1.x = f2bf(ea.x); e1.y = f2bf(ea.y); e1.z = f2bf(ea.z); e1.w = f2bf(ea.w);
            e2.x = f2bf(eb.x); e2.y = f2bf(eb.y); e2.z = f2bf(eb.z); e2.w = f2bf(eb.w);
            short* ed = a.enc16 + (size_t)row * DMODEL;
            *(short4v*)(ed + tid * 4)       = e1;
            *(short4v*)(ed + 256 + tid * 4) = e2;
        } else {
            int cb = v - 1024;
            int t = cb >> 7;
            int idx = ((cb & 127) * 256 + threadIdx.x) * 8;
            if (idx < a.wn[t]) {
                const float* s = a.wsrc[t] + idx;
                float4 p = *(const float4*)s;
                float4 q = *(const float4*)(s + 4);
                bf16x8 o;
                o[0] = f2bf(p.x); o[1] = f2bf(p.y); o[2] = f2bf(p.z); o[3] = f2bf(p.w);
                o[4] = f2bf(q.x); o[5] = f2bf(q.y); o[6] = f2bf(q.z); o[7] = f2bf(q.w);
                *(bf16x8*)(a.wdst[t] + idx) = o;
            }
        }
    }
    grid.sync();

    // ---- phase 1: fused {Q_self, KV_self, KV_cross} (independent, no sync between) ----
    {
        GJob j{a.qn16, a.wdst[0], nullptr, nullptr, a.q16, 512, 512, QSCALE, 0, 1, 512};
        for (int v = bx; v < j.ntile; v += nb) gemm_tile(j, v, AS0, BS0);
    }
    {
        GJob j{a.dec16, a.wdst[1], nullptr, nullptr, a.kv16, 1024, 512, 1.f, 0, 1, 1024};
        for (int v = bx; v < j.ntile; v += nb) gemm_tile(j, v, AS0, BS0);
    }
    {
        GJob j{a.enc16, a.wdst[5], nullptr, nullptr, a.kv16e, 1024, 512, 1.f, 0, 1, 1024};
        for (int v = bx; v < j.ntile; v += nb) gemm_tile(j, v, AS0, BS0);
    }
    grid.sync();

    // ---- phase 2: causal self-attention (1:1 block mapping, balanced bands) ----
    {
        int bh = bx & 31;
        int bsl = bx >> 5;
        int band = (bsl < 8) ? bsl : 23 - bsl;   // pairs bx and bx+256 to sum 15
        attn_block(a.q16, a.kv16, a.kv16 + 512, a.ao16, 1, band, bh, Kt, Vt, Pb);
    }
    grid.sync();

    // ---- phase 3: self out-proj + residual(dec) -> x1 fp32 ----
    {
        GJob j{a.ao16, a.wdst[4], nullptr, a.dec, a.x1, 512, 512, 1.f, 0, 0, 512};
        for (int v = bx; v < j.ntile; v += nb) gemm_tile(j, v, AS0, BS0);
    }
    grid.sync();

    // ---- phase 4: LN2 ----
#pragma unroll 1
    for (int v = bx; v < 1024; v += nb)
        ln_rows(a.x1, a.encln_g, a.encln_b, a.qn16, v * 4);
    grid.sync();

    // ---- phase 5: cross Q-proj ----
    {
        GJob j{a.qn16, a.wdst[6], nullptr, nullptr, a.q16, 512, 512, QSCALE, 0, 1, 512};
        for (int v = bx; v < j.ntile; v += nb) gemm_tile(j, v, AS0, BS0);
    }
    grid.sync();

    // ---- phase 6: cross attention ----
    {
        int bh = bx & 31;
        int bsl = bx >> 5;
        attn_block(a.q16, a.kv16e, a.kv16e + 512, a.ao16, 0, bsl, bh, Kt, Vt, Pb);
    }
    grid.sync();

    // ---- phase 7: cross out-proj + residual(x1) -> x2 fp32 ----
    {
        GJob j{a.ao16, a.wdst[9], nullptr, a.x1, a.x2, 512, 512, 1.f, 0, 0, 512};
        for (int v = bx; v < j.ntile; v += nb) gemm_tile(j, v, AS0, BS0);
    }
    grid.sync();

    // ---- phase 8: LN3 ----
#pragma unroll 1
    for (int v = bx; v < 1024; v += nb)
        ln_rows(a.x2, a.ffnln_g, a.ffnln_b, a.qn16, v * 4);
    grid.sync();

    // ---- phase 9: FFN1 (relu+bias) -> h16 ----
    {
        GJob j{a.qn16, a.wdst[8], a.fb1, nullptr, a.h16, 256, 512, 1.f, 1, 1, 256};
        for (int v = bx; v < j.ntile; v += nb) gemm_tile(j, v, AS0, BS0);
    }
    grid.sync();

    // ---- phase 10: FFN2 (+bias, +resid x2) -> out fp32 ----
    {
        GJob j{a.h16, a.wdst[7], a.fb2, a.x2, a.out, 512, 256, 1.f, 0, 0, 512};
        for (int v = bx; v < j.ntile; v += nb) gemm_tile(j, v, AS0, BS0);
    }
}

// ============================ Launch ============================
extern "C" void kernel_launch(void* const* d_in, const int* in_sizes, int n_in,
                              void* d_out, int out_size, void* d_ws, size_t ws_size,
                              hipStream_t stream) {
    const float* dec       = (const float*)d_in[0];
    const float* enc       = (const float*)d_in[1];
    const float* slf_Wq    = (const float*)d_in[3];
    const float* slf_Wk    = (const float*)d_in[4];
    const float* slf_Wv    = (const float*)d_in[5];
    const float* slf_Wfc   = (const float*)d_in[6];
    const float* slf_ln_g  = (const float*)d_in[7];
    const float* slf_ln_b  = (const float*)d_in[8];
    const float* enc_Wq    = (const float*)d_in[9];
    const float* enc_Wk    = (const float*)d_in[10];
    const float* enc_Wv    = (const float*)d_in[11];
    const float* enc_Wfc   = (const float*)d_in[12];
    const float* enc_ln_g  = (const float*)d_in[13];
    const float* enc_ln_b  = (const float*)d_in[14];
    const float* ffn_W1    = (const float*)d_in[15];
    const float* ffn_b1    = (const float*)d_in[16];
    const float* ffn_W2    = (const float*)d_in[17];
    const float* ffn_b2    = (const float*)d_in[18];
    const float* ffn_ln_g  = (const float*)d_in[19];
    const float* ffn_ln_b  = (const float*)d_in[20];
    float* out = (float*)d_out;

    const int Bb = 4, L = 1024, M = Bb * L;
    const size_t NE = (size_t)M * DMODEL;          // 2M
    const int WQN = NHEAD * DHEAD * DMODEL;        // 262144
    float* ws = (float*)d_ws;
    float* x1 = ws;
    float* x2 = ws + NE;
    short* kv16e = (short*)x2;     // alias: kv16e consumed (phase 6) before x2 written (phase 7)
    short* sb = (short*)(ws + 2 * NE);
    short* dec16 = sb;               sb += NE;
    short* enc16 = sb;               sb += NE;
    short* qn16  = sb;               sb += NE;
    short* q16   = sb;               sb += NE;
    short* ao16  = sb;               sb += NE;
    short* kv16  = sb;               sb += 2 * NE;
    short* h16   = sb;               sb += NE / 2;
    short* wq_s  = sb;               sb += WQN;
    short* wkv_s = sb;               sb += 2 * WQN;
    short* wfc_s = sb;               sb += WQN;
    short* wq_e  = sb;               sb += WQN;
    short* wkv_e = sb;               sb += 2 * WQN;
    short* wfc_e = sb;               sb += WQN;
    short* w1_16 = sb;               sb += 256 * DMODEL;
    short* w2_16 = sb;               sb += DMODEL * 256;

    MegaArgs ma;
    // weight cvt table; indices referenced in-kernel: 0=wq_s 1=wkv_s(K) 2=wkv_s+V
    // 3=wfc_s... kernel uses wdst[0]=wq_s, wdst[1]=wkv_s, wdst[4]=wfc_s,
    // wdst[5]=wkv_e, wdst[6]=wq_e, wdst[7]=w2, wdst[8]=w1, wdst[9]=wfc_e
    ma.wsrc[0] = slf_Wq;  ma.wdst[0] = wq_s;        ma.wn[0] = WQN;
    ma.wsrc[1] = slf_Wk;  ma.wdst[1] = wkv_s;       ma.wn[1] = WQN;
    ma.wsrc[2] = slf_Wv;  ma.wdst[2] = wkv_s + WQN; ma.wn[2] = WQN;
    ma.wsrc[3] = enc_Wk;  ma.wdst[3] = wkv_e;       ma.wn[3] = WQN;
    ma.wsrc[4] = slf_Wfc; ma.wdst[4] = wfc_s;       ma.wn[4] = WQN;
    ma.wsrc[5] = enc_Wv;  ma.wdst[5] = wkv_e + WQN; ma.wn[5] = WQN;
    ma.wsrc[6] = enc_Wq;  ma.wdst[6] = wq_e;        ma.wn[6] = WQN;
    ma.wsrc[7] = ffn_W2;  ma.wdst[7] = w2_16;       ma.wn[7] = DMODEL * 256;
    ma.wsrc[8] = ffn_W1;  ma.wdst[8] = w1_16;       ma.wn[8] = 256 * DMODEL;
    ma.wsrc[9] = enc_Wfc; ma.wdst[9] = wfc_e;       ma.wn[9] = WQN;
    // fix job-weight references: kernel phase 1 uses wdst[1] (kv_self base =
    // wkv_s, K at +0 / V at +WQN contiguous) and wdst[5]... but wdst[5] is
    // wkv_e+WQN (V half). Cross KV job needs base wkv_e -> use wdst[3].
    // Simplest: make wdst[5] the base by swapping table entries 3 and 5.
    ma.wsrc[5] = enc_Wk;  ma.wdst[5] = wkv_e;       ma.wn[5] = WQN;
    ma.wsrc[3] = enc_Wv;  ma.wdst[3] = wkv_e + WQN; ma.wn[3] = WQN;

    ma.dec = dec; ma.enc = enc;
    ma.slf_g = slf_ln_g; ma.slf_b = slf_ln_b;
    ma.encln_g = enc_ln_g; ma.encln_b = enc_ln_b;
    ma.ffnln_g = ffn_ln_g; ma.ffnln_b = ffn_ln_b;
    ma.fb1 = ffn_b1; ma.fb2 = ffn_b2;
    ma.qn16 = qn16; ma.dec16 = dec16; ma.enc16 = enc16;
    ma.q16 = q16; ma.ao16 = ao16;
    ma.kv16 = kv16; ma.kv16e = kv16e; ma.h16 = h16;
    ma.x1 = x1; ma.x2 = x2; ma.out = out;

    void* params[] = { &ma };
    hipLaunchCooperativeKernel((const void*)mega_kernel, dim3(512), dim3(256),
                               params, 0, stream);
}

// Round 10
// 256.559 us; speedup vs baseline: 3.2843x; 3.2843x over previous
//
#include <hip/hip_runtime.h>
#include <hip/hip_bf16.h>
#include <math.h>

#define DMODEL 512
#define NHEAD  8
#define DHEAD  64

typedef __attribute__((ext_vector_type(8))) short bf16x8;
typedef __attribute__((ext_vector_type(4))) float f32x4;
typedef __attribute__((ext_vector_type(4))) short short4v;

static __device__ inline short f2bf(float f) {
    __hip_bfloat16 h = __float2bfloat16(f);
    return *reinterpret_cast<short*>(&h);
}

#define GLOAD_LDS16(gp, lp)                                                      \
    __builtin_amdgcn_global_load_lds(                                            \
        (const __attribute__((address_space(1))) unsigned int*)(gp),             \
        (__attribute__((address_space(3))) unsigned int*)(lp), 16, 0, 0)

// ============================ prep: weight cvt + LN1 (+row converts) ============================
struct PrepArgs {
    const float* src[10];
    short*       dst[10];
    int          n[10];
    const float* X;
    const float* gam;
    const float* bet;
    short*       Y;
    short*       Xd;
    const float* E;
    short*       Ed;
    int          ln_blocks;
};

__global__ __launch_bounds__(256) void prep_kernel(PrepArgs a) {
    const int bx = blockIdx.x;
    if (bx < a.ln_blocks) {
        int row = bx * 4 + (threadIdx.x >> 6);
        int tid = threadIdx.x & 63;
        const float* x = a.X + (size_t)row * DMODEL;
        float4 v0 = *(const float4*)(x + tid * 4);
        float4 v1 = *(const float4*)(x + 256 + tid * 4);
        float sum = v0.x + v0.y + v0.z + v0.w + v1.x + v1.y + v1.z + v1.w;
        float sq  = v0.x*v0.x + v0.y*v0.y + v0.z*v0.z + v0.w*v0.w
                  + v1.x*v1.x + v1.y*v1.y + v1.z*v1.z + v1.w*v1.w;
#pragma unroll
        for (int off = 1; off < 64; off <<= 1) {
            sum += __shfl_xor(sum, off);
            sq  += __shfl_xor(sq, off);
        }
        float mu  = sum * (1.0f / DMODEL);
        float var = sq * (1.0f / DMODEL) - mu * mu;
        float r   = rsqrtf(var + 1e-6f);
        float4 g1 = *(const float4*)(a.gam + tid * 4);
        float4 c1 = *(const float4*)(a.bet + tid * 4);
        float4 g2 = *(const float4*)(a.gam + 256 + tid * 4);
        float4 c2 = *(const float4*)(a.bet + 256 + tid * 4);
        short4v y1, y2;
        y1.x = f2bf((v0.x - mu) * r * g1.x + c1.x);
        y1.y = f2bf((v0.y - mu) * r * g1.y + c1.y);
        y1.z = f2bf((v0.z - mu) * r * g1.z + c1.z);
        y1.w = f2bf((v0.w - mu) * r * g1.w + c1.w);
        y2.x = f2bf((v1.x - mu) * r * g2.x + c2.x);
        y2.y = f2bf((v1.y - mu) * r * g2.y + c2.y);
        y2.z = f2bf((v1.z - mu) * r * g2.z + c2.z);
        y2.w = f2bf((v1.w - mu) * r * g2.w + c2.w);
        short* y = a.Y + (size_t)row * DMODEL;
        *(short4v*)(y + tid * 4)       = y1;
        *(short4v*)(y + 256 + tid * 4) = y2;
        short4v d1, d2;
        d1.x = f2bf(v0.x); d1.y = f2bf(v0.y); d1.z = f2bf(v0.z); d1.w = f2bf(v0.w);
        d2.x = f2bf(v1.x); d2.y = f2bf(v1.y); d2.z = f2bf(v1.z); d2.w = f2bf(v1.w);
        short* d = a.Xd + (size_t)row * DMODEL;
        *(short4v*)(d + tid * 4)       = d1;
        *(short4v*)(d + 256 + tid * 4) = d2;
        const float* e = a.E + (size_t)row * DMODEL;
        float4 ea = *(const float4*)(e + tid * 4);
        float4 eb = *(const float4*)(e + 256 + tid * 4);
        short4v e1, e2;
        e1.x = f2bf(ea.x); e1.y = f2bf(ea.y); e1.z = f2bf(ea.z); e1.w = f2bf(ea.w);
        e2.x = f2bf(eb.x); e2.y = f2bf(eb.y); e2.z = f2bf(eb.z); e2.w = f2bf(eb.w);
        short* ed = a.Ed + (size_t)row * DMODEL;
        *(short4v*)(ed + tid * 4)       = e1;
        *(short4v*)(ed + 256 + tid * 4) = e2;
    } else {
        int cb = bx - a.ln_blocks;
        int t = cb >> 7;
        int idx = ((cb & 127) * 256 + threadIdx.x) * 8;
        if (idx >= a.n[t]) return;
        const float* s = a.src[t] + idx;
        float4 p = *(const float4*)s;
        float4 q = *(const float4*)(s + 4);
        bf16x8 o;
        o[0] = f2bf(p.x); o[1] = f2bf(p.y); o[2] = f2bf(p.z); o[3] = f2bf(p.w);
        o[4] = f2bf(q.x); o[5] = f2bf(q.y); o[6] = f2bf(q.z); o[7] = f2bf(q.w);
        *(bf16x8*)(a.dst[t] + idx) = o;
    }
}

// ============================ LayerNorm ============================
__global__ __launch_bounds__(256) void ln_kernel(const float* __restrict__ X,
                                                 const float* __restrict__ gam,
                                                 const float* __restrict__ bet,
                                                 short* __restrict__ Y) {
    int row = blockIdx.x * 4 + (threadIdx.x >> 6);
    int tid = threadIdx.x & 63;
    const float* x = X + (size_t)row * DMODEL;
    float4 a = *(const float4*)(x + tid * 4);
    float4 b = *(const float4*)(x + 256 + tid * 4);
    float sum = a.x + a.y + a.z + a.w + b.x + b.y + b.z + b.w;
    float sq  = a.x*a.x + a.y*a.y + a.z*a.z + a.w*a.w
              + b.x*b.x + b.y*b.y + b.z*b.z + b.w*b.w;
#pragma unroll
    for (int off = 1; off < 64; off <<= 1) {
        sum += __shfl_xor(sum, off);
        sq  += __shfl_xor(sq, off);
    }
    float mu  = sum * (1.0f / DMODEL);
    float var = sq * (1.0f / DMODEL) - mu * mu;
    float r   = rsqrtf(var + 1e-6f);
    float4 g1 = *(const float4*)(gam + tid * 4);
    float4 c1 = *(const float4*)(bet + tid * 4);
    float4 g2 = *(const float4*)(gam + 256 + tid * 4);
    float4 c2 = *(const float4*)(bet + 256 + tid * 4);
    short4v y1, y2;
    y1.x = f2bf((a.x - mu) * r * g1.x + c1.x);
    y1.y = f2bf((a.y - mu) * r * g1.y + c1.y);
    y1.z = f2bf((a.z - mu) * r * g1.z + c1.z);
    y1.w = f2bf((a.w - mu) * r * g1.w + c1.w);
    y2.x = f2bf((b.x - mu) * r * g2.x + c2.x);
    y2.y = f2bf((b.y - mu) * r * g2.y + c2.y);
    y2.z = f2bf((b.z - mu) * r * g2.z + c2.z);
    y2.w = f2bf((b.w - mu) * r * g2.w + c2.w);
    short* y = Y + (size_t)row * DMODEL;
    *(short4v*)(y + tid * 4)       = y1;
    *(short4v*)(y + 256 + tid * 4) = y2;
}

// ============================ bf16 MFMA GEMM (multi-job, 64x64, dbuf) ============================
struct GJobs {
    const short* A[3];
    const short* W[3];
    const float* bias[3];
    const float* resid[3];
    void*        C[3];
    int M[3], N[3], K[3];
    float scale[3];
    int relu[3], obf[3], nblk[3];
};

__global__ __launch_bounds__(256) void gemm_bf16(GJobs jb) {
    __shared__ short As[2][64 * 64];
    __shared__ short Bs[2][64 * 64];

    int bid = blockIdx.x, j = 0;
    while (j < 2 && bid >= jb.nblk[j]) { bid -= jb.nblk[j]; ++j; }
    const short* __restrict__ A = jb.A[j];
    const short* __restrict__ W = jb.W[j];
    const int N = jb.N[j], K = jb.K[j];
    const int nbx = N >> 6;
    const int tn = (bid % nbx) * 64;
    const int tm = (bid / nbx) * 64;

    const int tid  = threadIdx.x;
    const int w    = tid >> 6;
    const int l    = tid & 63;
    const int lq   = l & 15;
    const int g    = l >> 4;
    const int wm   = (w >> 1) * 32;
    const int wn   = (w & 1) * 32;
    const int lrow = l >> 3;
    const int lsl  = l & 7;

    f32x4 acc[2][2];
#pragma unroll
    for (int i = 0; i < 2; ++i)
#pragma unroll
        for (int jj = 0; jj < 2; ++jj)
            acc[i][jj] = (f32x4){0.f, 0.f, 0.f, 0.f};

#define GSTAGE(buf, koff)                                                        \
    do {                                                                         \
        _Pragma("unroll")                                                        \
        for (int i_ = 0; i_ < 2; ++i_) {                                         \
            int row_ = i_ * 32 + w * 8 + lrow;                                   \
            int slot_ = lsl ^ (row_ & 7);                                        \
            GLOAD_LDS16(A + (size_t)(tm + row_) * K + (koff) + slot_ * 8,        \
                        As[buf] + i_ * 2048 + w * 512);                          \
            GLOAD_LDS16(W + (size_t)(tn + row_) * K + (koff) + slot_ * 8,        \
                        Bs[buf] + i_ * 2048 + w * 512);                          \
        }                                                                        \
    } while (0)

    GSTAGE(0, 0);
    int buf = 0;
#pragma unroll 1
    for (int k0 = 0; k0 < K; k0 += 64, buf ^= 1) {
        __syncthreads();
        if (k0 + 64 < K) GSTAGE(buf ^ 1, k0 + 64);
#pragma unroll
        for (int ks = 0; ks < 2; ++ks) {
            const int sl = ((ks * 4 + g) ^ (lq & 7)) * 8;
            bf16x8 af[2], bfv[2];
#pragma unroll
            for (int i = 0; i < 2; ++i) {
                af[i]  = *(const bf16x8*)&As[buf][(wm + i * 16 + lq) * 64 + sl];
                bfv[i] = *(const bf16x8*)&Bs[buf][(wn + i * 16 + lq) * 64 + sl];
            }
#pragma unroll
            for (int i = 0; i < 2; ++i)
#pragma unroll
                for (int jj = 0; jj < 2; ++jj)
                    acc[i][jj] = __builtin_amdgcn_mfma_f32_16x16x32_bf16(
                        af[i], bfv[jj], acc[i][jj], 0, 0, 0);
        }
    }
#undef GSTAGE

    const float* bias  = jb.bias[j];
    const float* resid = jb.resid[j];
    const float scale  = jb.scale[j];
    const int relu = jb.relu[j], obf = jb.obf[j];
#pragma unroll
    for (int i = 0; i < 2; ++i) {
#pragma unroll
        for (int r = 0; r < 4; ++r) {
            int row = tm + wm + i * 16 + g * 4 + r;
#pragma unroll
            for (int jj = 0; jj < 2; ++jj) {
                int col = tn + wn + jj * 16 + lq;
                float v = acc[i][jj][r] * scale;
                if (bias)  v += bias[col];
                if (resid) v += resid[(size_t)row * N + col];
                if (relu)  v = fmaxf(v, 0.f);
                if (obf) ((short*)jb.C[j])[(size_t)row * N + col] = f2bf(v);
                else     ((float*)jb.C[j])[(size_t)row * N + col] = v;
            }
        }
    }
}

// ============================ MFMA flash attention (causal, direct) ============================
__global__ __launch_bounds__(256) void attn_mfma_kernel(
        const short* __restrict__ Q, const short* __restrict__ K,
        const short* __restrict__ V, short* __restrict__ O,
        int Lq, int Lk, int qs, int kvs) {
    __shared__ short Kt[64 * 64];
    __shared__ short Vt[64][72];
    __shared__ short Pb[4][16][72];

    const int tid  = threadIdx.x;
    const int wave = tid >> 6;
    const int lane = tid & 63;
    const int lq   = lane & 15;
    const int g    = lane >> 4;
    const int bh   = blockIdx.y;
    const int b = bh >> 3, h = bh & 7;
    const int band = (bh < 16) ? (int)blockIdx.x : (15 - (int)blockIdx.x);
    const int qt = band * 4 + wave;
    const int q0 = qt * 16;
    const float NEG = -__builtin_inff();

    size_t qoff = (size_t)(b * Lq + q0 + lq) * qs + h * DHEAD;
    bf16x8 qf0 = *(const bf16x8*)(Q + qoff + g * 8);
    bf16x8 qf1 = *(const bf16x8*)(Q + qoff + 32 + g * 8);

    f32x4 o[4] = {{0,0,0,0},{0,0,0,0},{0,0,0,0},{0,0,0,0}};
    f32x4 lacc = {0.f, 0.f, 0.f, 0.f};

    bf16x8 ones;
    {
        short ov = (lq == 0) ? (short)0x3F80 : (short)0;
#pragma unroll
        for (int i = 0; i < 8; ++i) ones[i] = ov;
    }

    const int nkt = band + 1;
    const int lrow = lane >> 3;
    const int lsl  = lane & 7;
    const int va = tid & 31;
    const int vd = (tid >> 5) * 8;

#pragma unroll 1
    for (int kt = 0; kt < nkt; ++kt) {
        __syncthreads();
#pragma unroll
        for (int i = 0; i < 2; ++i) {
            int row = i * 32 + wave * 8 + lrow;
            int slot = lsl ^ (row & 7);
            GLOAD_LDS16(K + (size_t)(b * Lk + kt * 64 + row) * kvs + h * DHEAD + slot * 8,
                        Kt + i * 2048 + wave * 512);
        }
        {
            size_t gb = (size_t)(b * Lk + kt * 64 + 2 * va) * kvs + h * DHEAD + vd;
            bf16x8 v0 = *(const bf16x8*)(V + gb);
            bf16x8 v1 = *(const bf16x8*)(V + gb + kvs);
#pragma unroll
            for (int i = 0; i < 8; ++i) {
                unsigned p = (unsigned short)v0[i] | ((unsigned)(unsigned short)v1[i] << 16);
                *(unsigned*)&Vt[vd + i][2 * va] = p;
            }
        }
        __syncthreads();

        f32x4 s[4];
#pragma unroll
        for (int sub = 0; sub < 4; ++sub) {
            int rr = sub * 16 + lq;
            const int sl0 = ((0 + g) ^ (lq & 7)) * 8;
            const int sl1 = ((4 + g) ^ (lq & 7)) * 8;
            bf16x8 kf0 = *(const bf16x8*)&Kt[rr * 64 + sl0];
            bf16x8 kf1 = *(const bf16x8*)&Kt[rr * 64 + sl1];
            f32x4 a = {0.f, 0.f, 0.f, 0.f};
            a = __builtin_amdgcn_mfma_f32_16x16x32_bf16(kf0, qf0, a, 0, 0, 0);
            a = __builtin_amdgcn_mfma_f32_16x16x32_bf16(kf1, qf1, a, 0, 0, 0);
            s[sub] = a;
        }
        if (kt == nkt - 1) {
            int qg = q0 + lq;
#pragma unroll
            for (int sub = 0; sub < 4; ++sub) {
#pragma unroll
                for (int r = 0; r < 4; ++r) {
                    int kg = kt * 64 + sub * 16 + g * 4 + r;
                    if (kg > qg) s[sub][r] = NEG;
                }
            }
        }

#pragma unroll
        for (int sub = 0; sub < 4; ++sub) {
            short4v p4;
            p4.x = f2bf(exp2f(fminf(s[sub][0], 85.f)));
            p4.y = f2bf(exp2f(fminf(s[sub][1], 85.f)));
            p4.z = f2bf(exp2f(fminf(s[sub][2], 85.f)));
            p4.w = f2bf(exp2f(fminf(s[sub][3], 85.f)));
            *(short4v*)&Pb[wave][lq][sub * 16 + g * 4] = p4;
        }
        bf16x8 pf0 = *(const bf16x8*)&Pb[wave][lq][g * 8];
        bf16x8 pf1 = *(const bf16x8*)&Pb[wave][lq][32 + g * 8];

#pragma unroll
        for (int dc = 0; dc < 4; ++dc) {
            bf16x8 vf0 = *(const bf16x8*)&Vt[dc * 16 + lq][g * 8];
            bf16x8 vf1 = *(const bf16x8*)&Vt[dc * 16 + lq][32 + g * 8];
            o[dc] = __builtin_amdgcn_mfma_f32_16x16x32_bf16(pf0, vf0, o[dc], 0, 0, 0);
            o[dc] = __builtin_amdgcn_mfma_f32_16x16x32_bf16(pf1, vf1, o[dc], 0, 0, 0);
        }
        lacc = __builtin_amdgcn_mfma_f32_16x16x32_bf16(pf0, ones, lacc, 0, 0, 0);
        lacc = __builtin_amdgcn_mfma_f32_16x16x32_bf16(pf1, ones, lacc, 0, 0, 0);
    }

#pragma unroll
    for (int r = 0; r < 4; ++r) {
        float lr = __shfl(lacc[r], g << 4);
        float inv = 1.f / lr;
        size_t ob = (size_t)(b * Lq + q0 + g * 4 + r) * qs + h * DHEAD + lq;
        O[ob + 0]  = f2bf(o[0][r] * inv);
        O[ob + 16] = f2bf(o[1][r] * inv);
        O[ob + 32] = f2bf(o[2][r] * inv);
        O[ob + 48] = f2bf(o[3][r] * inv);
    }
}

// ============================ split cross-attention: half keys -> partial U,l ============================
// Grid (16 bands, 32 bh, 2 halves). Writes unnormalized U (fp32, layout as O)
// and per-row l. Max-free softmax => partials combine exactly.
__global__ __launch_bounds__(256) void attn_split_kernel(
        const short* __restrict__ Q, const short* __restrict__ K,
        const short* __restrict__ V, float* __restrict__ U0,
        float* __restrict__ U1, float* __restrict__ L0, float* __restrict__ L1,
        int Lq, int Lk, int qs, int kvs) {
    __shared__ short Kt[64 * 64];
    __shared__ short Vt[64][72];
    __shared__ short Pb[4][16][72];

    const int tid  = threadIdx.x;
    const int wave = tid >> 6;
    const int lane = tid & 63;
    const int lq   = lane & 15;
    const int g    = lane >> 4;
    const int bh   = blockIdx.y;
    const int b = bh >> 3, h = bh & 7;
    const int half = blockIdx.z;
    const int qt = blockIdx.x * 4 + wave;
    const int q0 = qt * 16;
    float* __restrict__ U = half ? U1 : U0;
    float* __restrict__ Ls = half ? L1 : L0;

    size_t qoff = (size_t)(b * Lq + q0 + lq) * qs + h * DHEAD;
    bf16x8 qf0 = *(const bf16x8*)(Q + qoff + g * 8);
    bf16x8 qf1 = *(const bf16x8*)(Q + qoff + 32 + g * 8);

    f32x4 o[4] = {{0,0,0,0},{0,0,0,0},{0,0,0,0},{0,0,0,0}};
    f32x4 lacc = {0.f, 0.f, 0.f, 0.f};

    bf16x8 ones;
    {
        short ov = (lq == 0) ? (short)0x3F80 : (short)0;
#pragma unroll
        for (int i = 0; i < 8; ++i) ones[i] = ov;
    }

    const int kt0 = half * (Lk >> 7);      // half * 8
    const int kt1 = kt0 + (Lk >> 7);
    const int lrow = lane >> 3;
    const int lsl  = lane & 7;
    const int va = tid & 31;
    const int vd = (tid >> 5) * 8;

#pragma unroll 1
    for (int kt = kt0; kt < kt1; ++kt) {
        __syncthreads();
#pragma unroll
        for (int i = 0; i < 2; ++i) {
            int row = i * 32 + wave * 8 + lrow;
            int slot = lsl ^ (row & 7);
            GLOAD_LDS16(K + (size_t)(b * Lk + kt * 64 + row) * kvs + h * DHEAD + slot * 8,
                        Kt + i * 2048 + wave * 512);
        }
        {
            size_t gb = (size_t)(b * Lk + kt * 64 + 2 * va) * kvs + h * DHEAD + vd;
            bf16x8 v0 = *(const bf16x8*)(V + gb);
            bf16x8 v1 = *(const bf16x8*)(V + gb + kvs);
#pragma unroll
            for (int i = 0; i < 8; ++i) {
                unsigned p = (unsigned short)v0[i] | ((unsigned)(unsigned short)v1[i] << 16);
                *(unsigned*)&Vt[vd + i][2 * va] = p;
            }
        }
        __syncthreads();

        f32x4 s[4];
#pragma unroll
        for (int sub = 0; sub < 4; ++sub) {
            int rr = sub * 16 + lq;
            const int sl0 = ((0 + g) ^ (lq & 7)) * 8;
            const int sl1 = ((4 + g) ^ (lq & 7)) * 8;
            bf16x8 kf0 = *(const bf16x8*)&Kt[rr * 64 + sl0];
            bf16x8 kf1 = *(const bf16x8*)&Kt[rr * 64 + sl1];
            f32x4 a = {0.f, 0.f, 0.f, 0.f};
            a = __builtin_amdgcn_mfma_f32_16x16x32_bf16(kf0, qf0, a, 0, 0, 0);
            a = __builtin_amdgcn_mfma_f32_16x16x32_bf16(kf1, qf1, a, 0, 0, 0);
            s[sub] = a;
        }

#pragma unroll
        for (int sub = 0; sub < 4; ++sub) {
            short4v p4;
            p4.x = f2bf(exp2f(fminf(s[sub][0], 85.f)));
            p4.y = f2bf(exp2f(fminf(s[sub][1], 85.f)));
            p4.z = f2bf(exp2f(fminf(s[sub][2], 85.f)));
            p4.w = f2bf(exp2f(fminf(s[sub][3], 85.f)));
            *(short4v*)&Pb[wave][lq][sub * 16 + g * 4] = p4;
        }
        bf16x8 pf0 = *(const bf16x8*)&Pb[wave][lq][g * 8];
        bf16x8 pf1 = *(const bf16x8*)&Pb[wave][lq][32 + g * 8];

#pragma unroll
        for (int dc = 0; dc < 4; ++dc) {
            bf16x8 vf0 = *(const bf16x8*)&Vt[dc * 16 + lq][g * 8];
            bf16x8 vf1 = *(const bf16x8*)&Vt[dc * 16 + lq][32 + g * 8];
            o[dc] = __builtin_amdgcn_mfma_f32_16x16x32_bf16(pf0, vf0, o[dc], 0, 0, 0);
            o[dc] = __builtin_amdgcn_mfma_f32_16x16x32_bf16(pf1, vf1, o[dc], 0, 0, 0);
        }
        lacc = __builtin_amdgcn_mfma_f32_16x16x32_bf16(pf0, ones, lacc, 0, 0, 0);
        lacc = __builtin_amdgcn_mfma_f32_16x16x32_bf16(pf1, ones, lacc, 0, 0, 0);
    }

#pragma unroll
    for (int r = 0; r < 4; ++r) {
        float lr = __shfl(lacc[r], g << 4);
        int row = q0 + g * 4 + r;
        size_t ob = (size_t)(b * Lq + row) * qs + h * DHEAD + lq;
        U[ob + 0]  = o[0][r];
        U[ob + 16] = o[1][r];
        U[ob + 32] = o[2][r];
        U[ob + 48] = o[3][r];
        if (lq == 0) Ls[(size_t)(b * NHEAD + h) * Lq + row] = lr;
    }
}

// combine: ao16 = (U0+U1) / (l0+l1)
__global__ __launch_bounds__(256) void attn_combine_kernel(
        const float* __restrict__ U0, const float* __restrict__ U1,
        const float* __restrict__ L0, const float* __restrict__ L1,
        short* __restrict__ O) {
    size_t idx = ((size_t)blockIdx.x * 256 + threadIdx.x) * 8;
    int rowflat = (int)(idx >> 9);          // b*1024 + q
    int b = rowflat >> 10;
    int q = rowflat & 1023;
    int h = (int)((idx >> 6) & 7);
    float l = L0[(size_t)(b * NHEAD + h) * 1024 + q] +
              L1[(size_t)(b * NHEAD + h) * 1024 + q];
    float inv = 1.f / l;
    float4 a0 = *(const float4*)(U0 + idx);
    float4 a1 = *(const float4*)(U0 + idx + 4);
    float4 b0 = *(const float4*)(U1 + idx);
    float4 b1 = *(const float4*)(U1 + idx + 4);
    bf16x8 o;
    o[0] = f2bf((a0.x + b0.x) * inv);
    o[1] = f2bf((a0.y + b0.y) * inv);
    o[2] = f2bf((a0.z + b0.z) * inv);
    o[3] = f2bf((a0.w + b0.w) * inv);
    o[4] = f2bf((a1.x + b1.x) * inv);
    o[5] = f2bf((a1.y + b1.y) * inv);
    o[6] = f2bf((a1.z + b1.z) * inv);
    o[7] = f2bf((a1.w + b1.w) * inv);
    *(bf16x8*)(O + idx) = o;
}

// ============================ Launch ============================
static void launch_gemm(GJobs& jb, int njobs, hipStream_t stream) {
    int total = 0;
    for (int i = 0; i < 3; ++i) { if (i >= njobs) jb.nblk[i] = 0; total += jb.nblk[i]; }
    gemm_bf16<<<total, 256, 0, stream>>>(jb);
}

extern "C" void kernel_launch(void* const* d_in, const int* in_sizes, int n_in,
                              void* d_out, int out_size, void* d_ws, size_t ws_size,
                              hipStream_t stream) {
    const float* dec       = (const float*)d_in[0];
    const float* enc       = (const float*)d_in[1];
    const float* slf_Wq    = (const float*)d_in[3];
    const float* slf_Wk    = (const float*)d_in[4];
    const float* slf_Wv    = (const float*)d_in[5];
    const float* slf_Wfc   = (const float*)d_in[6];
    const float* slf_ln_g  = (const float*)d_in[7];
    const float* slf_ln_b  = (const float*)d_in[8];
    const float* enc_Wq    = (const float*)d_in[9];
    const float* enc_Wk    = (const float*)d_in[10];
    const float* enc_Wv    = (const float*)d_in[11];
    const float* enc_Wfc   = (const float*)d_in[12];
    const float* enc_ln_g  = (const float*)d_in[13];
    const float* enc_ln_b  = (const float*)d_in[14];
    const float* ffn_W1    = (const float*)d_in[15];
    const float* ffn_b1    = (const float*)d_in[16];
    const float* ffn_W2    = (const float*)d_in[17];
    const float* ffn_b2    = (const float*)d_in[18];
    const float* ffn_ln_g  = (const float*)d_in[19];
    const float* ffn_ln_b  = (const float*)d_in[20];
    float* out = (float*)d_out;

    const int Bb = 4, L = 1024, M = Bb * L;
    const size_t NE = (size_t)M * DMODEL;          // 2M
    const int WQN = NHEAD * DHEAD * DMODEL;        // 262144
    const float QSCALE = 0.125f * 1.44269504f;     // 1/sqrt(dk) * log2(e)
    float* ws = (float*)d_ws;
    float* x1 = ws;
    float* x2 = ws + NE;
    short* kv16e = (short*)x2;     // alias: consumed (attn2) before x2 written
    short* sb = (short*)(ws + 2 * NE);
    short* dec16 = sb;               sb += NE;
    short* enc16 = sb;               sb += NE;
    short* qn16  = sb;               sb += NE;
    short* q16   = sb;               sb += NE;
    short* ao16  = sb;               sb += NE;
    short* kv16  = sb;               sb += 2 * NE;
    short* h16   = sb;               sb += NE / 2;
    short* wq_s  = sb;               sb += WQN;
    short* wkv_s = sb;               sb += 2 * WQN;
    short* wfc_s = sb;               sb += WQN;
    short* wq_e  = sb;               sb += WQN;
    short* wkv_e = sb;               sb += 2 * WQN;
    short* wfc_e = sb;               sb += WQN;
    short* w1_16 = sb;               sb += 256 * DMODEL;
    short* w2_16 = sb;               sb += DMODEL * 256;
    float* l0    = (float*)sb;       sb += 2 * M;      // 4096*8 floats
    float* l1    = (float*)sb;       sb += 2 * M;
    // U buffers alias regions dead by the time attn2 runs:
    float* u0 = (float*)kv16;        // kv16 (8MB) free after attn1
    float* u1 = (float*)dec16;       // dec16+enc16 (8MB contiguous) free after QKV

    // ---- prep: weight cvt + LN1 + dec/enc converts ----
    PrepArgs pa;
    pa.src[0] = slf_Wq;  pa.dst[0] = wq_s;          pa.n[0] = WQN;
    pa.src[1] = slf_Wk;  pa.dst[1] = wkv_s;         pa.n[1] = WQN;
    pa.src[2] = slf_Wv;  pa.dst[2] = wkv_s + WQN;   pa.n[2] = WQN;
    pa.src[3] = slf_Wfc; pa.dst[3] = wfc_s;         pa.n[3] = WQN;
    pa.src[4] = enc_Wq;  pa.dst[4] = wq_e;          pa.n[4] = WQN;
    pa.src[5] = enc_Wk;  pa.dst[5] = wkv_e;         pa.n[5] = WQN;
    pa.src[6] = enc_Wv;  pa.dst[6] = wkv_e + WQN;   pa.n[6] = WQN;
    pa.src[7] = enc_Wfc; pa.dst[7] = wfc_e;         pa.n[7] = WQN;
    pa.src[8] = ffn_W1;  pa.dst[8] = w1_16;         pa.n[8] = 256 * DMODEL;
    pa.src[9] = ffn_W2;  pa.dst[9] = w2_16;         pa.n[9] = DMODEL * 256;
    pa.X = dec; pa.gam = slf_ln_g; pa.bet = slf_ln_b; pa.Y = qn16;
    pa.Xd = dec16; pa.E = enc; pa.Ed = enc16;
    pa.ln_blocks = M / 4;
    prep_kernel<<<M / 4 + 10 * 128, 256, 0, stream>>>(pa);

    dim3 attn_grid(L / 64, Bb * NHEAD);
    dim3 attn2_grid(L / 64, Bb * NHEAD, 2);
    const int NB512  = (M / 64) * (512 / 64);    // 512
    const int NB1024 = (M / 64) * (1024 / 64);   // 1024
    const int NB256  = (M / 64) * (256 / 64);    // 256

    // ---- fused {Q_self, KV_self, KV_cross} ----
    {
        GJobs jb = {};
        jb.A[0] = qn16;  jb.W[0] = wq_s;  jb.C[0] = q16;
        jb.M[0] = M; jb.N[0] = 512;  jb.K[0] = 512; jb.scale[0] = QSCALE;
        jb.obf[0] = 1; jb.nblk[0] = NB512;
        jb.A[1] = dec16; jb.W[1] = wkv_s; jb.C[1] = kv16;
        jb.M[1] = M; jb.N[1] = 1024; jb.K[1] = 512; jb.scale[1] = 1.f;
        jb.obf[1] = 1; jb.nblk[1] = NB1024;
        jb.A[2] = enc16; jb.W[2] = wkv_e; jb.C[2] = kv16e;
        jb.M[2] = M; jb.N[2] = 1024; jb.K[2] = 512; jb.scale[2] = 1.f;
        jb.obf[2] = 1; jb.nblk[2] = NB1024;
        launch_gemm(jb, 3, stream);
    }
    attn_mfma_kernel<<<attn_grid, 256, 0, stream>>>(q16, kv16, kv16 + 512, ao16,
                                                    L, L, DMODEL, 1024);
    {
        GJobs jb = {};
        jb.A[0] = ao16; jb.W[0] = wfc_s; jb.resid[0] = dec; jb.C[0] = x1;
        jb.M[0] = M; jb.N[0] = 512; jb.K[0] = 512; jb.scale[0] = 1.f;
        jb.obf[0] = 0; jb.nblk[0] = NB512;
        launch_gemm(jb, 1, stream);
    }

    // ---- cross attention ----
    ln_kernel<<<M / 4, 256, 0, stream>>>(x1, enc_ln_g, enc_ln_b, qn16);
    {
        GJobs jb = {};
        jb.A[0] = qn16; jb.W[0] = wq_e; jb.C[0] = q16;
        jb.M[0] = M; jb.N[0] = 512; jb.K[0] = 512; jb.scale[0] = QSCALE;
        jb.obf[0] = 1; jb.nblk[0] = NB512;
        launch_gemm(jb, 1, stream);
    }
    attn_split_kernel<<<attn2_grid, 256, 0, stream>>>(q16, kv16e, kv16e + 512,
                                                      u0, u1, l0, l1,
                                                      L, L, DMODEL, 1024);
    attn_combine_kernel<<<NE / 2048, 256, 0, stream>>>(u0, u1, l0, l1, ao16);
    {
        GJobs jb = {};
        jb.A[0] = ao16; jb.W[0] = wfc_e; jb.resid[0] = x1; jb.C[0] = x2;
        jb.M[0] = M; jb.N[0] = 512; jb.K[0] = 512; jb.scale[0] = 1.f;
        jb.obf[0] = 0; jb.nblk[0] = NB512;
        launch_gemm(jb, 1, stream);
    }

    // ---- FFN ----
    ln_kernel<<<M / 4, 256, 0, stream>>>(x2, ffn_ln_g, ffn_ln_b, qn16);
    {
        GJobs jb = {};
        jb.A[0] = qn16; jb.W[0] = w1_16; jb.bias[0] = ffn_b1; jb.C[0] = h16;
        jb.M[0] = M; jb.N[0] = 256; jb.K[0] = 512; jb.scale[0] = 1.f;
        jb.relu[0] = 1; jb.obf[0] = 1; jb.nblk[0] = NB256;
        launch_gemm(jb, 1, stream);
    }
    {
        GJobs jb = {};
        jb.A[0] = h16; jb.W[0] = w2_16; jb.bias[0] = ffn_b2; jb.resid[0] = x2;
        jb.C[0] = out;
        jb.M[0] = M; jb.N[0] = 512; jb.K[0] = 256; jb.scale[0] = 1.f;
        jb.obf[0] = 0; jb.nblk[0] = NB512;
        launch_gemm(jb, 1, stream);
    }
}